// Round 1
// baseline (3305.257 us; speedup 1.0000x reference)
//
#include <hip/hip_runtime.h>
#include <hip/hip_bf16.h>

// 3-layer LSTM encoder. B=512, T=512, F=8, HID=128, EMB=64.
// Layer-by-layer; recurrence kernels hold Whh rows in registers (thread t owns
// gate-column t), input projections are separate parallel GEMMs chunked over T.
// ws layout: [xp bf16 512*128*512][O bf16 512*512*128][hstate f32][cstate f32]

#define DEVI __device__ __forceinline__

static constexpr int T_ = 512, BATCH_ = 512, HID_ = 128, EMB_ = 64, TC_ = 128;

DEVI float sigmoidf_(float x) {
    return __builtin_amdgcn_rcpf(1.f + __builtin_amdgcn_exp2f(x * -1.44269504f));
}
DEVI float tanhf_(float x) {
    return 2.f * __builtin_amdgcn_rcpf(1.f + __builtin_amdgcn_exp2f(x * -2.88539008f)) - 1.f;
}
DEVI float b2f_lo(unsigned int u) { union { unsigned int i; float f; } x; x.i = u << 16; return x.f; }
DEVI float b2f_hi(unsigned int u) { union { unsigned int i; float f; } x; x.i = u & 0xffff0000u; return x.f; }

// ---------------- recurrence kernel ----------------
// LAYER=1: 512 thr, G=512, H=128, full T, fused K=8 input proj from x (fp32)
// LAYER=2: 512 thr, G=512, H=128, Tc=128 chunks, xp bf16 input, writes O in place
// LAYER=3: 256 thr, G=256, H=64,  Tc=128 chunks, xp bf16 input, writes d_out at t=T-1
template <int LAYER>
__launch_bounds__(LAYER == 3 ? 256 : 512)
__global__ void recur_k(const float* __restrict__ x, const float* __restrict__ Wih1,
                        const float* __restrict__ bih, const float* __restrict__ bhh,
                        const float* __restrict__ Whh, const __hip_bfloat16* __restrict__ xp,
                        __hip_bfloat16* __restrict__ O, float* __restrict__ hstate,
                        float* __restrict__ cstate, float* __restrict__ out, int chunk) {
    constexpr int THREADS = (LAYER == 3) ? 256 : 512;
    constexpr int G = THREADS;          // gate count = 4*H
    constexpr int H = (LAYER == 3) ? 64 : 128;
    constexpr int BB = 2;               // batch rows per block
    constexpr int TC = (LAYER == 1) ? 512 : TC_;

    const int tid = threadIdx.x;
    const int b0 = blockIdx.x * BB;
    const int gtype = tid / (G / 4);    // 0:i 1:f 2:g 3:o

    __shared__ float h_lds[BB][H];
    __shared__ float g_lds[BB][G];

    // recurrent weight row for this thread's gate column
    float w[H];
#pragma unroll
    for (int k = 0; k < H; k += 4) {
        const float4 w4 = *reinterpret_cast<const float4*>(Whh + (size_t)tid * H + k);
        w[k] = w4.x; w[k + 1] = w4.y; w[k + 2] = w4.z; w[k + 3] = w4.w;
    }

    float wi[8];
    float bias = 0.f;
    if constexpr (LAYER == 1) {
#pragma unroll
        for (int k = 0; k < 8; k++) wi[k] = Wih1[tid * 8 + k];
        bias = bih[tid] + bhh[tid];
    }

    const int pb = tid / H, pj = tid % H;   // pointwise mapping (tid < BB*H)
    float creg = 0.f;
    if (chunk == 0) {
        for (int i = tid; i < BB * H; i += THREADS) ((float*)h_lds)[i] = 0.f;
    } else {
        if (tid < BB * H) {
            creg = cstate[(size_t)(b0 + pb) * H + pj];
            h_lds[pb][pj] = hstate[(size_t)(b0 + pb) * H + pj];
        }
    }
    __syncthreads();

    for (int t = 0; t < TC; t++) {
        const int gt = chunk * TC + t;
#pragma unroll
        for (int b = 0; b < BB; b++) {
            float xv;   // input-projection contribution (loaded early, added late)
            float a0 = 0.f, a1 = 0.f;
            if constexpr (LAYER == 1) {
                const float4 xlo = *reinterpret_cast<const float4*>(x + ((size_t)(b0 + b) * T_ + gt) * 8);
                const float4 xhi = *reinterpret_cast<const float4*>(x + ((size_t)(b0 + b) * T_ + gt) * 8 + 4);
                float p0 = bias + wi[0] * xlo.x + wi[1] * xlo.y + wi[2] * xlo.z + wi[3] * xlo.w;
                float p1 = wi[4] * xhi.x + wi[5] * xhi.y + wi[6] * xhi.z + wi[7] * xhi.w;
                xv = p0 + p1;
            } else {
                xv = __bfloat162float(xp[((size_t)(b0 + b) * TC + t) * G + tid]);
            }
#pragma unroll
            for (int k = 0; k < H; k += 8) {
                const float4 h0 = *reinterpret_cast<const float4*>(&h_lds[b][k]);
                const float4 h1 = *reinterpret_cast<const float4*>(&h_lds[b][k + 4]);
                a0 += w[k] * h0.x;     a0 += w[k + 1] * h0.y;
                a0 += w[k + 2] * h0.z; a0 += w[k + 3] * h0.w;
                a1 += w[k + 4] * h1.x; a1 += w[k + 5] * h1.y;
                a1 += w[k + 6] * h1.z; a1 += w[k + 7] * h1.w;
            }
            const float v = xv + a0 + a1;
            g_lds[b][tid] = (gtype == 2) ? tanhf_(v) : sigmoidf_(v);
        }
        __syncthreads();
        if (tid < BB * H) {
            const float gi = g_lds[pb][pj];
            const float gf = g_lds[pb][pj + H];
            const float gg = g_lds[pb][pj + 2 * H];
            const float go = g_lds[pb][pj + 3 * H];
            creg = gf * creg + gi * gg;
            const float h = go * tanhf_(creg);
            h_lds[pb][pj] = h;
            if constexpr (LAYER < 3) {
                O[((size_t)(b0 + pb) * T_ + gt) * HID_ + pj] = __float2bfloat16(h);
            } else {
                if (gt == T_ - 1) out[(size_t)(b0 + pb) * EMB_ + pj] = h;
            }
        }
        __syncthreads();
    }

    if constexpr (LAYER >= 2) {
        if (tid < BB * H) {
            cstate[(size_t)(b0 + pb) * H + pj] = creg;
            hstate[(size_t)(b0 + pb) * H + pj] = h_lds[pb][pj];
        }
    }
}

// ---------------- input-projection GEMM ----------------
// xp[b][t'][g] = sum_k In[b][c*TC+t'][k] * W[g][k] + bih[g] + bhh[g]
template <int G>
__launch_bounds__(256)
__global__ void proj_k(const __hip_bfloat16* __restrict__ In, const float* __restrict__ W,
                       const float* __restrict__ bih, const float* __restrict__ bhh,
                       __hip_bfloat16* __restrict__ xp, int chunk) {
    constexpr int ROWS = 16, K = 128;
    constexpr int NCG = G / 256;
    const int tid = threadIdx.x;
    const int rb = blockIdx.x / NCG;
    const int cg = blockIdx.x % NCG;
    const int g = cg * 256 + tid;

    __shared__ float in_lds[ROWS][K];
    {
        const int ri = tid >> 4;
        const int k8 = (tid & 15) << 3;
        const int r = rb * ROWS + ri;
        const int b = r / TC_, tt = r % TC_;
        const int gt = chunk * TC_ + tt;
        const uint4 v = *reinterpret_cast<const uint4*>(In + ((size_t)b * T_ + gt) * HID_ + k8);
        in_lds[ri][k8 + 0] = b2f_lo(v.x); in_lds[ri][k8 + 1] = b2f_hi(v.x);
        in_lds[ri][k8 + 2] = b2f_lo(v.y); in_lds[ri][k8 + 3] = b2f_hi(v.y);
        in_lds[ri][k8 + 4] = b2f_lo(v.z); in_lds[ri][k8 + 5] = b2f_hi(v.z);
        in_lds[ri][k8 + 6] = b2f_lo(v.w); in_lds[ri][k8 + 7] = b2f_hi(v.w);
    }
    __syncthreads();

    const float bias = bih[g] + bhh[g];
    float acc[ROWS];
#pragma unroll
    for (int r = 0; r < ROWS; r++) acc[r] = bias;

    const float4* W4 = reinterpret_cast<const float4*>(W + (size_t)g * K);
#pragma unroll 4
    for (int k4 = 0; k4 < K / 4; k4++) {
        const float4 w4 = W4[k4];
#pragma unroll
        for (int r = 0; r < ROWS; r++) {
            const float4 iv = *reinterpret_cast<const float4*>(&in_lds[r][k4 * 4]);
            acc[r] += w4.x * iv.x + w4.y * iv.y + w4.z * iv.z + w4.w * iv.w;
        }
    }

    const int r0 = rb * ROWS;
#pragma unroll
    for (int r = 0; r < ROWS; r++) {
        const int rr = r0 + r;
        const int b = rr / TC_, tt = rr % TC_;
        xp[((size_t)b * TC_ + tt) * G + g] = __float2bfloat16(acc[r]);
    }
}

extern "C" void kernel_launch(void* const* d_in, const int* in_sizes, int n_in,
                              void* d_out, int out_size, void* d_ws, size_t ws_size,
                              hipStream_t stream) {
    const float* x    = (const float*)d_in[0];
    const float* Wih1 = (const float*)d_in[1];
    const float* Whh1 = (const float*)d_in[2];
    const float* bih1 = (const float*)d_in[3];
    const float* bhh1 = (const float*)d_in[4];
    const float* Wih2 = (const float*)d_in[5];
    const float* Whh2 = (const float*)d_in[6];
    const float* bih2 = (const float*)d_in[7];
    const float* bhh2 = (const float*)d_in[8];
    const float* Wih3 = (const float*)d_in[9];
    const float* Whh3 = (const float*)d_in[10];
    const float* bih3 = (const float*)d_in[11];
    const float* bhh3 = (const float*)d_in[12];
    float* out = (float*)d_out;

    char* ws = (char*)d_ws;
    __hip_bfloat16* xp = (__hip_bfloat16*)ws;                       // 67,108,864 B
    __hip_bfloat16* O  = (__hip_bfloat16*)(ws + (size_t)67108864);  // 67,108,864 B
    float* hstate = (float*)(ws + (size_t)134217728);               // 262,144 B
    float* cstate = (float*)(ws + (size_t)134217728 + 262144);      // 262,144 B
    (void)ws_size; (void)in_sizes; (void)n_in; (void)out_size;

    // layer 1: single launch over all T (K=8 projection fused)
    recur_k<1><<<256, 512, 0, stream>>>(x, Wih1, bih1, bhh1, Whh1, nullptr, O,
                                        nullptr, nullptr, nullptr, 0);
    // layer 2: chunked proj + recurrence, O overwritten in place
    for (int c = 0; c < 4; c++) {
        proj_k<512><<<4096 * 2, 256, 0, stream>>>(O, Wih2, bih2, bhh2, xp, c);
        recur_k<2><<<256, 512, 0, stream>>>(nullptr, nullptr, nullptr, nullptr, Whh2, xp,
                                            O, hstate, cstate, nullptr, c);
    }
    // layer 3
    for (int c = 0; c < 4; c++) {
        proj_k<256><<<4096, 256, 0, stream>>>(O, Wih3, bih3, bhh3, xp, c);
        recur_k<3><<<256, 256, 0, stream>>>(nullptr, nullptr, nullptr, nullptr, Whh3, xp,
                                            nullptr, hstate, cstate, out, c);
    }
}

// Round 3
// 1624.535 us; speedup vs baseline: 2.0346x; 2.0346x over previous
//
#include <hip/hip_runtime.h>
#include <hip/hip_bf16.h>

// 3-layer LSTM encoder. B=512, T=512, F=8, HID=128, EMB=64.
// Recurrence: 1 batch/block, 256 thr, gates 2/thread (L1/L2) or 1/thread (L3),
// Whh f16-packed VGPR-resident, v_dot2_f32_f16, 4 independent acc chains,
// h in LDS f16. Input projections: MFMA 16x16x32 f16 GEMM chunked over T.
// ws: [O f16 67MB][xp f16 33.5MB][hstate][cstate][Wih2h][Wih3h] = 101.4MB

#define DEVI __device__ __forceinline__

typedef _Float16 h2 __attribute__((ext_vector_type(2)));
typedef _Float16 h8 __attribute__((ext_vector_type(8)));
typedef float f4 __attribute__((ext_vector_type(4)));

static constexpr int T_ = 512, B_ = 512, HID_ = 128, EMB_ = 64;

DEVI float sigmoidf_(float x) {
    return __builtin_amdgcn_rcpf(1.f + __builtin_amdgcn_exp2f(x * -1.44269504f));
}
DEVI float tanhf_(float x) {
    return 2.f * __builtin_amdgcn_rcpf(1.f + __builtin_amdgcn_exp2f(x * -2.88539008f)) - 1.f;
}

DEVI float dot2(h2 a, h2 b, float c) {
#if __has_builtin(__builtin_amdgcn_fdot2)
    return __builtin_amdgcn_fdot2(a, b, c, false);
#else
    return c + (float)a.x * (float)b.x + (float)a.y * (float)b.y;
#endif
}

// ---------------- recurrence, layers 1 & 2 (G=512, H=128) ----------------
// MODE 0: layer 1, full T, K=8 input proj fused from x (fp32, staged in LDS)
// MODE 1: layer 2, TC=64 chunks, xp f16 input (bias pre-folded by proj)
template <int MODE>
__launch_bounds__(256, 2)
__global__ void recur12_k(const float* __restrict__ x, const float* __restrict__ Wih1,
                          const float* __restrict__ bih1, const float* __restrict__ bhh1,
                          const float* __restrict__ Whh, const _Float16* __restrict__ xp,
                          _Float16* __restrict__ O, float* __restrict__ hstate,
                          float* __restrict__ cstate, int chunk) {
    constexpr int G = 512, H = 128;
    constexpr int TC = (MODE == 0) ? T_ : 64;
    const int tid = threadIdx.x;
    const int b = blockIdx.x;

    __shared__ __align__(16) _Float16 h_lds[H];
    __shared__ __align__(16) float g_lds[G];
    __shared__ __align__(16) float x_lds[(MODE == 0) ? T_ * 8 : 4];

    // two gate rows per thread: g0 = tid (i/f), g1 = tid+256 (g/o), f16-packed
    h2 w0[64], w1[64];
    {
        const float2* r0 = reinterpret_cast<const float2*>(Whh + (size_t)tid * H);
        const float2* r1 = reinterpret_cast<const float2*>(Whh + (size_t)(tid + 256) * H);
#pragma unroll
        for (int k = 0; k < 64; k++) {
            const float2 a = r0[k];
            const float2 c = r1[k];
            w0[k] = h2{(_Float16)a.x, (_Float16)a.y};
            w1[k] = h2{(_Float16)c.x, (_Float16)c.y};
        }
    }
#pragma unroll
    for (int k = 0; k < 64; k++) {  // pin in VGPRs: forbid re-load inside loop
        asm volatile("" : "+v"(w0[k]));
        asm volatile("" : "+v"(w1[k]));
    }

    float wi0[8], wi1[8], bias0 = 0.f, bias1 = 0.f;
    if constexpr (MODE == 0) {
#pragma unroll
        for (int k = 0; k < 8; k++) {
            wi0[k] = Wih1[tid * 8 + k];
            wi1[k] = Wih1[(tid + 256) * 8 + k];
        }
#pragma unroll
        for (int k = 0; k < 8; k++) {
            asm volatile("" : "+v"(wi0[k]));
            asm volatile("" : "+v"(wi1[k]));
        }
        bias0 = bih1[tid] + bhh1[tid];
        bias1 = bih1[tid + 256] + bhh1[tid + 256];
        const float4* xb = reinterpret_cast<const float4*>(x + (size_t)b * (T_ * 8));
        for (int i = tid; i < T_ * 8 / 4; i += 256)
            reinterpret_cast<float4*>(x_lds)[i] = xb[i];
    }

    float c = 0.f;
    if (MODE == 1 && chunk > 0) {
        if (tid < H) {
            c = cstate[(size_t)b * H + tid];
            h_lds[tid] = (_Float16)hstate[(size_t)b * H + tid];
        }
    } else {
        if (tid < H) h_lds[tid] = (_Float16)0.f;
    }
    __syncthreads();

    float xv0 = 0.f, xv1 = 0.f;
    if constexpr (MODE == 1) {
        const size_t base = (size_t)b * TC * G;
        xv0 = (float)xp[base + tid];
        xv1 = (float)xp[base + tid + 256];
    }

    for (int t = 0; t < TC; t++) {
        float s0, s1;
        if constexpr (MODE == 0) {
            const float4 xa = reinterpret_cast<const float4*>(x_lds)[t * 2];
            const float4 xc = reinterpret_cast<const float4*>(x_lds)[t * 2 + 1];
            s0 = bias0 + wi0[0] * xa.x + wi0[1] * xa.y + wi0[2] * xa.z + wi0[3] * xa.w
                       + wi0[4] * xc.x + wi0[5] * xc.y + wi0[6] * xc.z + wi0[7] * xc.w;
            s1 = bias1 + wi1[0] * xa.x + wi1[1] * xa.y + wi1[2] * xa.z + wi1[3] * xa.w
                       + wi1[4] * xc.x + wi1[5] * xc.y + wi1[6] * xc.z + wi1[7] * xc.w;
        } else {
            s0 = xv0; s1 = xv1;
            const int tn = (t + 1 < TC) ? t + 1 : TC - 1;  // prefetch next step
            const size_t base = ((size_t)b * TC + tn) * G;
            xv0 = (float)xp[base + tid];
            xv1 = (float)xp[base + tid + 256];
        }
        float4 hv[16];
#pragma unroll
        for (int k = 0; k < 16; k++) hv[k] = reinterpret_cast<const float4*>(h_lds)[k];
        // 4 independent dot chains (32 dot2 each)
        float a0a = 0.f, a0b = 0.f, a1a = 0.f, a1b = 0.f;
#pragma unroll
        for (int k = 0; k < 16; k += 2) {
            const h2* h0 = reinterpret_cast<const h2*>(&hv[k]);
            const h2* h1 = reinterpret_cast<const h2*>(&hv[k + 1]);
            a0a = dot2(w0[4 * k + 0], h0[0], a0a); a1a = dot2(w1[4 * k + 0], h0[0], a1a);
            a0a = dot2(w0[4 * k + 1], h0[1], a0a); a1a = dot2(w1[4 * k + 1], h0[1], a1a);
            a0a = dot2(w0[4 * k + 2], h0[2], a0a); a1a = dot2(w1[4 * k + 2], h0[2], a1a);
            a0a = dot2(w0[4 * k + 3], h0[3], a0a); a1a = dot2(w1[4 * k + 3], h0[3], a1a);
            a0b = dot2(w0[4 * k + 4], h1[0], a0b); a1b = dot2(w1[4 * k + 4], h1[0], a1b);
            a0b = dot2(w0[4 * k + 5], h1[1], a0b); a1b = dot2(w1[4 * k + 5], h1[1], a1b);
            a0b = dot2(w0[4 * k + 6], h1[2], a0b); a1b = dot2(w1[4 * k + 6], h1[2], a1b);
            a0b = dot2(w0[4 * k + 7], h1[3], a0b); a1b = dot2(w1[4 * k + 7], h1[3], a1b);
        }
        const float v0 = s0 + a0a + a0b;
        const float v1 = s1 + a1a + a1b;
        g_lds[tid] = sigmoidf_(v0);                                  // i or f gate
        g_lds[tid + 256] = (tid < 128) ? tanhf_(v1) : sigmoidf_(v1); // g or o gate
        __syncthreads();
        if (tid < H) {
            const float gi = g_lds[tid], gf = g_lds[tid + 128];
            const float gg = g_lds[tid + 256], go = g_lds[tid + 384];
            c = gf * c + gi * gg;
            const float h = go * tanhf_(c);
            h_lds[tid] = (_Float16)h;
            const int gt = (MODE == 0) ? t : chunk * TC + t;
            O[((size_t)b * T_ + gt) * HID_ + tid] = (_Float16)h;
        }
        __syncthreads();
    }

    if constexpr (MODE == 1) {
        if (tid < H) {
            cstate[(size_t)b * H + tid] = c;
            hstate[(size_t)b * H + tid] = (float)h_lds[tid];
        }
    }
}

// ---------------- recurrence, layer 3 (G=256, H=64) ----------------
__launch_bounds__(256, 2)
__global__ void recur3_k(const float* __restrict__ Whh, const _Float16* __restrict__ xp,
                         float* __restrict__ hstate, float* __restrict__ cstate,
                         float* __restrict__ out, int chunk) {
    constexpr int G = 256, H = 64, TC = 128;
    const int tid = threadIdx.x;
    const int b = blockIdx.x;

    __shared__ __align__(16) _Float16 h_lds[H];
    __shared__ __align__(16) float g_lds[G];

    h2 w[32];
    {
        const float2* r = reinterpret_cast<const float2*>(Whh + (size_t)tid * H);
#pragma unroll
        for (int k = 0; k < 32; k++) {
            const float2 a = r[k];
            w[k] = h2{(_Float16)a.x, (_Float16)a.y};
        }
    }
#pragma unroll
    for (int k = 0; k < 32; k++) asm volatile("" : "+v"(w[k]));

    float c = 0.f;
    if (chunk > 0) {
        if (tid < H) {
            c = cstate[(size_t)b * H + tid];
            h_lds[tid] = (_Float16)hstate[(size_t)b * H + tid];
        }
    } else {
        if (tid < H) h_lds[tid] = (_Float16)0.f;
    }
    __syncthreads();

    float xv = (float)xp[(size_t)b * TC * G + tid];
    for (int t = 0; t < TC; t++) {
        const float s = xv;
        const int tn = (t + 1 < TC) ? t + 1 : TC - 1;
        xv = (float)xp[((size_t)b * TC + tn) * G + tid];
        float4 hv[8];
#pragma unroll
        for (int k = 0; k < 8; k++) hv[k] = reinterpret_cast<const float4*>(h_lds)[k];
        float aa = 0.f, ab = 0.f;
#pragma unroll
        for (int k = 0; k < 8; k += 2) {
            const h2* h0 = reinterpret_cast<const h2*>(&hv[k]);
            const h2* h1 = reinterpret_cast<const h2*>(&hv[k + 1]);
            aa = dot2(w[4 * k + 0], h0[0], aa); ab = dot2(w[4 * k + 4], h1[0], ab);
            aa = dot2(w[4 * k + 1], h0[1], aa); ab = dot2(w[4 * k + 5], h1[1], ab);
            aa = dot2(w[4 * k + 2], h0[2], aa); ab = dot2(w[4 * k + 6], h1[2], ab);
            aa = dot2(w[4 * k + 3], h0[3], aa); ab = dot2(w[4 * k + 7], h1[3], ab);
        }
        const float v = s + aa + ab;
        g_lds[tid] = (tid >> 6 == 2) ? tanhf_(v) : sigmoidf_(v);
        __syncthreads();
        if (tid < H) {
            const float gi = g_lds[tid], gf = g_lds[tid + 64];
            const float gg = g_lds[tid + 128], go = g_lds[tid + 192];
            c = gf * c + gi * gg;
            const float h = go * tanhf_(c);
            h_lds[tid] = (_Float16)h;
            const int gt = chunk * TC + t;
            if (gt == T_ - 1) out[(size_t)b * EMB_ + tid] = h;
        }
        __syncthreads();
    }
    if (tid < H) {
        cstate[(size_t)b * H + tid] = c;
        hstate[(size_t)b * H + tid] = (float)h_lds[tid];
    }
}

// ---------------- input-projection GEMM (MFMA f16) ----------------
// xp[row][g] = In[row'][0:128] . Wh[g][0:128] + bih[g] + bhh[g]
// row = b*TC + t', In row' = b*T + chunk*TC + t'. M = B*TC, N = G, K = 128.
template <int G, int TC>
__launch_bounds__(256)
__global__ void proj_k(const _Float16* __restrict__ In, const _Float16* __restrict__ Wh,
                       const float* __restrict__ bih, const float* __restrict__ bhh,
                       _Float16* __restrict__ xp, int chunk) {
    constexpr int K = 128;
    constexpr int NB = G / 128;
    const int tid = threadIdx.x;
    const int lane = tid & 63, wid = tid >> 6;
    const int mb = blockIdx.x / NB, nb = blockIdx.x % NB;
    const int m0 = mb * 128 + (wid >> 1) * 64;
    const int n0 = nb * 128 + (wid & 1) * 64;
    const int lrow = lane & 15, lk8 = (lane >> 4) * 8;

    f4 acc[4][4] = {};
#pragma unroll
    for (int ks = 0; ks < 4; ks++) {
        const int k0 = ks * 32 + lk8;
        h8 af[4], bf[4];
#pragma unroll
        for (int mt = 0; mt < 4; mt++) {
            const int row = m0 + mt * 16 + lrow;
            const int bb = row / TC, tt = row % TC;
            af[mt] = *reinterpret_cast<const h8*>(In + ((size_t)bb * T_ + chunk * TC + tt) * HID_ + k0);
        }
#pragma unroll
        for (int nt = 0; nt < 4; nt++) {
            const int g = n0 + nt * 16 + lrow;
            bf[nt] = *reinterpret_cast<const h8*>(Wh + (size_t)g * K + k0);
        }
#pragma unroll
        for (int mt = 0; mt < 4; mt++)
#pragma unroll
            for (int nt = 0; nt < 4; nt++)
                acc[mt][nt] = __builtin_amdgcn_mfma_f32_16x16x32_f16(af[mt], bf[nt], acc[mt][nt], 0, 0, 0);
    }
#pragma unroll
    for (int nt = 0; nt < 4; nt++) {
        const int g = n0 + nt * 16 + lrow;
        const float bias = bih[g] + bhh[g];
#pragma unroll
        for (int mt = 0; mt < 4; mt++) {
#pragma unroll
            for (int j = 0; j < 4; j++) {
                const int row = m0 + mt * 16 + (lane >> 4) * 4 + j;
                xp[(size_t)row * G + g] = (_Float16)(acc[mt][nt][j] + bias);
            }
        }
    }
}

// f32 -> f16 weight conversion
__global__ void wprep_k(const float* __restrict__ W, _Float16* __restrict__ Wh, int n4) {
    const int i = blockIdx.x * 256 + threadIdx.x;
    if (i < n4) {
        const float4 v = reinterpret_cast<const float4*>(W)[i];
        h2* o = reinterpret_cast<h2*>(Wh) + i * 2;
        o[0] = h2{(_Float16)v.x, (_Float16)v.y};
        o[1] = h2{(_Float16)v.z, (_Float16)v.w};
    }
}

extern "C" void kernel_launch(void* const* d_in, const int* in_sizes, int n_in,
                              void* d_out, int out_size, void* d_ws, size_t ws_size,
                              hipStream_t stream) {
    const float* x    = (const float*)d_in[0];
    const float* Wih1 = (const float*)d_in[1];
    const float* Whh1 = (const float*)d_in[2];
    const float* bih1 = (const float*)d_in[3];
    const float* bhh1 = (const float*)d_in[4];
    const float* Whh2 = (const float*)d_in[6];
    const float* Whh3 = (const float*)d_in[10];
    float* out = (float*)d_out;

    char* ws = (char*)d_ws;
    _Float16* O      = (_Float16*)ws;                                  // 67,108,864 B [512][512][128]
    _Float16* xp     = (_Float16*)(ws + (size_t)67108864);             // 33,554,432 B
    float* hstate    = (float*)(ws + (size_t)100663296);               // 262,144 B
    float* cstate    = (float*)(ws + (size_t)100925440);               // 262,144 B
    _Float16* Wih2h  = (_Float16*)(ws + (size_t)101187584);            // 131,072 B
    _Float16* Wih3h  = (_Float16*)(ws + (size_t)101318656);            // 65,536 B
    (void)ws_size; (void)in_sizes; (void)n_in; (void)out_size;

    wprep_k<<<64, 256, 0, stream>>>((const float*)d_in[5], Wih2h, 16384);
    wprep_k<<<32, 256, 0, stream>>>((const float*)d_in[9], Wih3h, 8192);

    // layer 1: fused input proj, full T
    recur12_k<0><<<512, 256, 0, stream>>>(x, Wih1, bih1, bhh1, Whh1, nullptr, O,
                                          nullptr, nullptr, 0);
    // layer 2: 8 chunks of TC=64 (xp fits in 33.5 MB)
    for (int c = 0; c < 8; c++) {
        proj_k<512, 64><<<1024, 256, 0, stream>>>(O, Wih2h, (const float*)d_in[7],
                                                  (const float*)d_in[8], xp, c);
        recur12_k<1><<<512, 256, 0, stream>>>(nullptr, nullptr, nullptr, nullptr, Whh2,
                                              xp, O, hstate, cstate, c);
    }
    // layer 3: 4 chunks of TC=128
    for (int c = 0; c < 4; c++) {
        proj_k<256, 128><<<1024, 256, 0, stream>>>(O, Wih3h, (const float*)d_in[11],
                                                   (const float*)d_in[12], xp, c);
        recur3_k<<<512, 256, 0, stream>>>(Whh3, xp, hstate, cstate, out, c);
    }
}